// Round 4
// baseline (6024.132 us; speedup 1.0000x reference)
//
#include <hip/hip_runtime.h>
#include <math.h>

#define NPTS  65536
#define DIM   256
#define NC    512
#define NITER 10

// ---------------- workspace layout (float offsets) ----------------
#define WS_C      0                       // clusters        512*256 f32
#define WS_WSUM   (WS_C + NC*DIM)         // weighted sums   512*256 f32
#define WS_COUNTS (WS_WSUM + NC*DIM)      // counts          512 f32
#define WS_W2     (WS_COUNTS + NC)        // ||w||^2         65536 f32
#define WS_C2     (WS_W2 + NPTS)          // ||c||^2         512 f32
#define WS_DONE   (WS_C2 + NC)            // done flag (int) [+pad to 16B]
#define WS_CHI    (WS_DONE + 4)           // C hi split      512*256 bf16 (65536 f32 slots)
#define WS_CLO    (WS_CHI + NC*DIM/2)     // C lo split      512*256 bf16

typedef __attribute__((ext_vector_type(8))) short bf16x8;
typedef __attribute__((ext_vector_type(4))) float f32x4;

// fp32 -> bf16 RNE, and back (manual: avoids __hip_bfloat16 ABI differences)
__device__ __forceinline__ unsigned short f2bf(float x) {
  unsigned u = __float_as_uint(x);
  u += 0x7fffu + ((u >> 16) & 1u);
  return (unsigned short)(u >> 16);
}
__device__ __forceinline__ float bf2f(unsigned short h) {
  return __uint_as_float(((unsigned)h) << 16);
}

// ---------------- init: C = W[0:512], done = 0 ----------------
__global__ void k_init(const float* __restrict__ W, float* __restrict__ C, int* __restrict__ done) {
  int i = blockIdx.x * 256 + threadIdx.x;
  C[i] = W[i];
  if (i == 0) *done = 0;
}

// ---------------- row norms of W (wave per row) ----------------
__global__ void k_w2(const float* __restrict__ W, float* __restrict__ w2) {
  int row  = blockIdx.x * 4 + (threadIdx.x >> 6);
  int lane = threadIdx.x & 63;
  float4 v = *(const float4*)(W + (size_t)row * DIM + 4 * lane);
  float s = v.x*v.x + v.y*v.y + v.z*v.z + v.w*v.w;
  #pragma unroll
  for (int o = 32; o; o >>= 1) s += __shfl_down(s, o);
  if (lane == 0) w2[row] = s;
}

// ---------------- per-iter prep: c2, C bf16 split, zero wsum/counts ----------------
__global__ void k_prep(const float* __restrict__ C, float* __restrict__ c2,
                       float* __restrict__ wsum, float* __restrict__ counts,
                       unsigned short* __restrict__ Chi, unsigned short* __restrict__ Clo) {
  __shared__ float wsh[4];
  int b = blockIdx.x, t = threadIdx.x;
  float v = C[b * DIM + t];
  // bf16 hi/lo split of C
  unsigned short h = f2bf(v);
  Chi[b * DIM + t] = h;
  Clo[b * DIM + t] = f2bf(v - bf2f(h));
  float s = v * v;
  #pragma unroll
  for (int o = 32; o; o >>= 1) s += __shfl_down(s, o);
  if ((t & 63) == 0) wsh[t >> 6] = s;
  __syncthreads();
  if (t == 0) c2[b] = wsh[0] + wsh[1] + wsh[2] + wsh[3];
  wsum[b * DIM + t] = 0.f;
  if (t == 0) counts[b] = 0.f;
}

// ---------------- fused distances + softmax + counts via split-bf16 MFMA ----
// Block: 256 thr = 4 waves; wave handles 16 rows x all 512 clusters, K=256.
// S = W.C^T via mfma_f32_16x16x32_bf16 with hi/lo split (3 MFMA per k-chunk).
// Two passes: (A) rowSum of e=exp(-sqrt(d2)); (B) recompute, normalize, store.
__launch_bounds__(256, 4)
__global__ void k_attn(const float* __restrict__ W,
                       const unsigned short* __restrict__ Chi,
                       const unsigned short* __restrict__ Clo,
                       const float* __restrict__ w2, const float* __restrict__ c2,
                       float* __restrict__ attn, float* __restrict__ counts,
                       const int* __restrict__ done)
{
  if (*done) return;
  __shared__ float cnt_lds[NC];
  const int t    = threadIdx.x;
  const int wave = t >> 6;
  const int l    = t & 63;
  const int lx   = l & 15;     // A-row / B-col / D-col within tile
  const int gy   = l >> 4;     // k-group; D-row group

  cnt_lds[t] = 0.f; cnt_lds[t + 256] = 0.f;
  __syncthreads();

  const int rowW = blockIdx.x * 64 + wave * 16;   // wave's 16 rows

  // ---- build A fragments (this wave's W rows, bf16 hi/lo) : 64 VGPR ----
  bf16x8 ah[8], al[8];
  {
    const float* wrow = W + (size_t)(rowW + lx) * DIM;
    #pragma unroll
    for (int kc = 0; kc < 8; ++kc) {
      const float* p = wrow + kc * 32 + gy * 8;
      float4 v0 = *(const float4*)p;
      float4 v1 = *(const float4*)(p + 4);
      float xs[8] = {v0.x, v0.y, v0.z, v0.w, v1.x, v1.y, v1.z, v1.w};
      #pragma unroll
      for (int j = 0; j < 8; ++j) {
        unsigned short h = f2bf(xs[j]);
        ah[kc][j] = (short)h;
        al[kc][j] = (short)f2bf(xs[j] - bf2f(h));
      }
    }
  }
  float w2r[4];
  #pragma unroll
  for (int r = 0; r < 4; ++r) w2r[r] = w2[rowW + gy * 4 + r];

  // ---- pass A: softmax denominators ----
  float rowP[4] = {0.f, 0.f, 0.f, 0.f};
  for (int ct = 0; ct < 32; ++ct) {
    f32x4 acc = {0.f, 0.f, 0.f, 0.f};
    const unsigned short* bh0 = Chi + ((ct * 16 + lx) << 8) + gy * 8;
    const unsigned short* bl0 = Clo + ((ct * 16 + lx) << 8) + gy * 8;
    #pragma unroll
    for (int kc = 0; kc < 8; ++kc) {
      bf16x8 bh = *(const bf16x8*)(bh0 + kc * 32);
      bf16x8 bl = *(const bf16x8*)(bl0 + kc * 32);
      acc = __builtin_amdgcn_mfma_f32_16x16x32_bf16(ah[kc], bh, acc, 0, 0, 0);
      acc = __builtin_amdgcn_mfma_f32_16x16x32_bf16(al[kc], bh, acc, 0, 0, 0);
      acc = __builtin_amdgcn_mfma_f32_16x16x32_bf16(ah[kc], bl, acc, 0, 0, 0);
    }
    float c2v = c2[ct * 16 + lx];
    #pragma unroll
    for (int r = 0; r < 4; ++r) {
      float d2 = w2r[r] + c2v - 2.f * acc[r];
      rowP[r] += __expf(-sqrtf(fmaxf(d2, 1e-12f)));
    }
  }
  // reduce across the 16 col-lanes (rows identical within each 16-lane group)
  #pragma unroll
  for (int m = 1; m < 16; m <<= 1) {
    #pragma unroll
    for (int r = 0; r < 4; ++r) rowP[r] += __shfl_xor(rowP[r], m);
  }
  float rinv[4];
  #pragma unroll
  for (int r = 0; r < 4; ++r) rinv[r] = 1.f / rowP[r];

  // ---- pass B: recompute, normalize, store, counts ----
  for (int ct = 0; ct < 32; ++ct) {
    f32x4 acc = {0.f, 0.f, 0.f, 0.f};
    const unsigned short* bh0 = Chi + ((ct * 16 + lx) << 8) + gy * 8;
    const unsigned short* bl0 = Clo + ((ct * 16 + lx) << 8) + gy * 8;
    #pragma unroll
    for (int kc = 0; kc < 8; ++kc) {
      bf16x8 bh = *(const bf16x8*)(bh0 + kc * 32);
      bf16x8 bl = *(const bf16x8*)(bl0 + kc * 32);
      acc = __builtin_amdgcn_mfma_f32_16x16x32_bf16(ah[kc], bh, acc, 0, 0, 0);
      acc = __builtin_amdgcn_mfma_f32_16x16x32_bf16(al[kc], bh, acc, 0, 0, 0);
      acc = __builtin_amdgcn_mfma_f32_16x16x32_bf16(ah[kc], bl, acc, 0, 0, 0);
    }
    float c2v = c2[ct * 16 + lx];
    float csum = 0.f;
    #pragma unroll
    for (int r = 0; r < 4; ++r) {
      float d2 = w2r[r] + c2v - 2.f * acc[r];
      float a  = __expf(-sqrtf(fmaxf(d2, 1e-12f))) * rinv[r];
      attn[(size_t)(rowW + gy * 4 + r) * NC + ct * 16 + lx] = a;
      csum += a;
    }
    csum += __shfl_xor(csum, 16);
    csum += __shfl_xor(csum, 32);
    if (l < 16) atomicAdd(&cnt_lds[ct * 16 + l], csum);
  }
  __syncthreads();
  atomicAdd(&counts[t],       cnt_lds[t]);
  atomicAdd(&counts[t + 256], cnt_lds[t + 256]);
}

// ---------------- wsum = attn^T @ W (K-split, atomic epilogue) ----------------
__launch_bounds__(256, 2)
__global__ void k_wsum(const float* __restrict__ attn, const float* __restrict__ W,
                       float* __restrict__ wsum, const int* __restrict__ done)
{
  if (*done) return;
  __shared__ float At[64*64];
  __shared__ float Bt[64*64];
  const int t = threadIdx.x, tx = t & 15, ty = t >> 4;
  const int ctile = blockIdx.x & 7;
  const int dtile = (blockIdx.x >> 3) & 3;
  const int kch   = blockIdx.x >> 5;
  const int c0 = ctile*64, d0 = dtile*64;
  const size_t rbase = (size_t)kch * 2048;
  float acc[4][4] = {{0}};
  for (int kk = 0; kk < 2048; kk += 64) {
    __syncthreads();
    #pragma unroll
    for (int p = 0; p < 4; ++p) {
      int q = p*256 + t;
      int kr = q >> 4, c4 = q & 15;
      size_t row = rbase + kk + kr;
      *(float4*)&At[kr*64 + 4*c4] = *(const float4*)(attn + row*NC  + c0 + 4*c4);
      *(float4*)&Bt[kr*64 + 4*c4] = *(const float4*)(W    + row*DIM + d0 + 4*c4);
    }
    __syncthreads();
    #pragma unroll 8
    for (int k = 0; k < 64; ++k) {
      float4 av = *(const float4*)&At[k*64 + 4*ty];
      float4 bv = *(const float4*)&Bt[k*64 + 4*tx];
      acc[0][0]+=av.x*bv.x; acc[0][1]+=av.x*bv.y; acc[0][2]+=av.x*bv.z; acc[0][3]+=av.x*bv.w;
      acc[1][0]+=av.y*bv.x; acc[1][1]+=av.y*bv.y; acc[1][2]+=av.y*bv.z; acc[1][3]+=av.y*bv.w;
      acc[2][0]+=av.z*bv.x; acc[2][1]+=av.z*bv.y; acc[2][2]+=av.z*bv.z; acc[2][3]+=av.z*bv.w;
      acc[3][0]+=av.w*bv.x; acc[3][1]+=av.w*bv.y; acc[3][2]+=av.w*bv.z; acc[3][3]+=av.w*bv.w;
    }
  }
  #pragma unroll
  for (int i = 0; i < 4; ++i)
    #pragma unroll
    for (int j = 0; j < 4; ++j)
      atomicAdd(&wsum[(size_t)(c0 + 4*ty + i)*DIM + d0 + 4*tx + j], acc[i][j]);
}

// ---------------- cluster update + convergence ----------------
__global__ void k_update(float* __restrict__ C, const float* __restrict__ wsum,
                         const float* __restrict__ counts, int* __restrict__ done)
{
  if (*done) return;
  __shared__ float wsh[16];
  __shared__ float nrm2;
  int t = threadIdx.x;  // 1024
  float local = 0.f;
  for (int p = 0; p < 128; ++p) {
    int i = p*1024 + t;
    float cn = wsum[i] / counts[i >> 8];
    float d  = C[i] - cn;
    local += d * d;
  }
  #pragma unroll
  for (int o = 32; o; o >>= 1) local += __shfl_down(local, o);
  if ((t & 63) == 0) wsh[t >> 6] = local;
  __syncthreads();
  if (t == 0) {
    float s = 0.f;
    #pragma unroll
    for (int x = 0; x < 16; ++x) s += wsh[x];
    nrm2 = s;
  }
  __syncthreads();
  if (nrm2 <= 1e-8f) {
    if (t == 0) *done = 1;
  } else {
    for (int p = 0; p < 128; ++p) {
      int i = p*1024 + t;
      C[i] = wsum[i] / counts[i >> 8];
    }
  }
}

// ---------------- compressed = attn @ C ----------------
__device__ __forceinline__ int swz64(int k, int c) {
  return (k << 6) + (c ^ (((k >> 2) & 15) << 2));
}
__launch_bounds__(256, 2)
__global__ void k_compress(const float* __restrict__ attn, const float* __restrict__ C,
                           float* __restrict__ out)
{
  __shared__ float At[64*64];
  __shared__ float Bt[64*64];
  const int t = threadIdx.x, tx = t & 15, ty = t >> 4;
  const int rt = blockIdx.x >> 2;
  const int dt = blockIdx.x & 3;
  const int r0 = rt*64, d0 = dt*64;
  float acc[4][4] = {{0}};
  for (int kc = 0; kc < 8; ++kc) {
    __syncthreads();
    #pragma unroll
    for (int p = 0; p < 4; ++p) {
      int q = p*256 + t;
      int r = q >> 4, x4 = q & 15;
      float4 v = *(const float4*)(attn + (size_t)(r0 + r)*NC + kc*64 + 4*x4);
      At[swz64(4*x4+0, r)] = v.x;
      At[swz64(4*x4+1, r)] = v.y;
      At[swz64(4*x4+2, r)] = v.z;
      At[swz64(4*x4+3, r)] = v.w;
      *(float4*)&Bt[r*64 + 4*x4] = *(const float4*)(C + (size_t)(kc*64 + r)*DIM + d0 + 4*x4);
    }
    __syncthreads();
    #pragma unroll 8
    for (int k = 0; k < 64; ++k) {
      float4 av = *(const float4*)&At[swz64(k, 4*ty)];
      float4 bv = *(const float4*)&Bt[k*64 + 4*tx];
      acc[0][0]+=av.x*bv.x; acc[0][1]+=av.x*bv.y; acc[0][2]+=av.x*bv.z; acc[0][3]+=av.x*bv.w;
      acc[1][0]+=av.y*bv.x; acc[1][1]+=av.y*bv.y; acc[1][2]+=av.y*bv.z; acc[1][3]+=av.y*bv.w;
      acc[2][0]+=av.z*bv.x; acc[2][1]+=av.z*bv.y; acc[2][2]+=av.z*bv.z; acc[2][3]+=av.z*bv.w;
      acc[3][0]+=av.w*bv.x; acc[3][1]+=av.w*bv.y; acc[3][2]+=av.w*bv.z; acc[3][3]+=av.w*bv.w;
    }
  }
  #pragma unroll
  for (int i = 0; i < 4; ++i) {
    float4 o = {acc[i][0], acc[i][1], acc[i][2], acc[i][3]};
    *(float4*)(out + (size_t)(r0 + 4*ty + i)*DIM + d0 + 4*tx) = o;
  }
}

__global__ void k_copy(const float* __restrict__ C, float* __restrict__ out) {
  int i = blockIdx.x * 256 + threadIdx.x;
  out[i] = C[i];
}

extern "C" void kernel_launch(void* const* d_in, const int* in_sizes, int n_in,
                              void* d_out, int out_size, void* d_ws, size_t ws_size,
                              hipStream_t stream)
{
  const float* W = (const float*)d_in[0];
  float* out = (float*)d_out;
  float* compressed   = out;
  float* out_clusters = out + (size_t)NPTS * DIM;
  float* attn         = out_clusters + NC * DIM;

  float* ws     = (float*)d_ws;
  float* C      = ws + WS_C;
  float* wsum   = ws + WS_WSUM;
  float* counts = ws + WS_COUNTS;
  float* w2     = ws + WS_W2;
  float* c2     = ws + WS_C2;
  int*   done   = (int*)(ws + WS_DONE);
  unsigned short* Chi = (unsigned short*)(ws + WS_CHI);
  unsigned short* Clo = (unsigned short*)(ws + WS_CLO);

  k_init<<<NC*DIM/256, 256, 0, stream>>>(W, C, done);
  k_w2<<<NPTS/4, 256, 0, stream>>>(W, w2);
  for (int it = 0; it < NITER; ++it) {
    k_prep<<<NC, 256, 0, stream>>>(C, c2, wsum, counts, Chi, Clo);
    k_attn<<<NPTS/64, 256, 0, stream>>>(W, Chi, Clo, w2, c2, attn, counts, done);
    k_wsum<<<1024, 256, 0, stream>>>(attn, W, wsum, done);
    k_update<<<1, 1024, 0, stream>>>(C, wsum, counts, done);
  }
  k_compress<<<(NPTS/64)*(DIM/64), 256, 0, stream>>>(attn, C, compressed);
  k_copy<<<NC*DIM/256, 256, 0, stream>>>(C, out_clusters);
}

// Round 5
// 4359.545 us; speedup vs baseline: 1.3818x; 1.3818x over previous
//
#include <hip/hip_runtime.h>
#include <math.h>

#define NPTS  65536
#define DIM   256
#define NC    512
#define NITER 10

// ---------------- workspace layout (float offsets) ----------------
#define WS_C      0                       // clusters        512*256 f32
#define WS_WSUM   (WS_C + NC*DIM)         // weighted sums   512*256 f32
#define WS_COUNTS (WS_WSUM + NC*DIM)      // counts          512 f32
#define WS_W2     (WS_COUNTS + NC)        // ||w||^2         65536 f32
#define WS_C2     (WS_W2 + NPTS)          // ||c||^2         512 f32
#define WS_DONE   (WS_C2 + NC)            // done flag (int) [+pad]
#define WS_CHI    (WS_DONE + 4)           // C hi split      512*256 bf16
#define WS_CLO    (WS_CHI + NC*DIM/2)     // C lo split      512*256 bf16

typedef __attribute__((ext_vector_type(8))) short bf16x8;
typedef __attribute__((ext_vector_type(4))) float f32x4;

__device__ __forceinline__ unsigned short f2bf(float x) {
  unsigned u = __float_as_uint(x);
  u += 0x7fffu + ((u >> 16) & 1u);
  return (unsigned short)(u >> 16);
}
__device__ __forceinline__ float bf2f(unsigned short h) {
  return __uint_as_float(((unsigned)h) << 16);
}

// ---------------- init: C = W[0:512], done = 0 ----------------
__global__ void k_init(const float* __restrict__ W, float* __restrict__ C, int* __restrict__ done) {
  int i = blockIdx.x * 256 + threadIdx.x;
  C[i] = W[i];
  if (i == 0) *done = 0;
}

// ---------------- row norms of W ----------------
__global__ void k_w2(const float* __restrict__ W, float* __restrict__ w2) {
  int row  = blockIdx.x * 4 + (threadIdx.x >> 6);
  int lane = threadIdx.x & 63;
  float4 v = *(const float4*)(W + (size_t)row * DIM + 4 * lane);
  float s = v.x*v.x + v.y*v.y + v.z*v.z + v.w*v.w;
  #pragma unroll
  for (int o = 32; o; o >>= 1) s += __shfl_down(s, o);
  if (lane == 0) w2[row] = s;
}

// ---------------- per-iter prep: c2, C bf16 split, zero wsum/counts ----------------
__global__ void k_prep(const float* __restrict__ C, float* __restrict__ c2,
                       float* __restrict__ wsum, float* __restrict__ counts,
                       unsigned short* __restrict__ Chi, unsigned short* __restrict__ Clo) {
  __shared__ float wsh[4];
  int b = blockIdx.x, t = threadIdx.x;
  float v = C[b * DIM + t];
  unsigned short h = f2bf(v);
  Chi[b * DIM + t] = h;
  Clo[b * DIM + t] = f2bf(v - bf2f(h));
  float s = v * v;
  #pragma unroll
  for (int o = 32; o; o >>= 1) s += __shfl_down(s, o);
  if ((t & 63) == 0) wsh[t >> 6] = s;
  __syncthreads();
  if (t == 0) c2[b] = wsh[0] + wsh[1] + wsh[2] + wsh[3];
  wsum[b * DIM + t] = 0.f;
  if (t == 0) counts[b] = 0.f;
}

// ---------------- fused distances + softmax + counts (split-bf16 MFMA) ----------
// 1024 blocks x 256 thr (4 waves). Block = 64 rows x all 512 clusters.
// Phase 1: single pass over 32 cluster-tiles (16 clusters each), C tile staged
//   in LDS (k-major layout -> conflict-free b128 on both sides), double-buffered
//   reg-staging; 3 independent MFMA chains (hi*hi, lo*hi, hi*lo); e = exp(-d)
//   stored unnormalized to attn; per-row sums accumulated in registers.
// Phase 2: re-read own 128 KB block of attn (L2-hot), scale by 1/rowSum,
//   write back coalesced float4, accumulate counts.
__launch_bounds__(256, 4)
__global__ void k_attn(const float* __restrict__ W,
                       const unsigned short* __restrict__ Chi,
                       const unsigned short* __restrict__ Clo,
                       const float* __restrict__ w2, const float* __restrict__ c2,
                       float* __restrict__ attn, float* __restrict__ counts,
                       const int* __restrict__ done)
{
  if (*done) return;
  __shared__ unsigned short Bh[2][4096];   // 2 x 8 KB, layout [kc:8][r:16][gy:4][8 bf16]
  __shared__ unsigned short Bl[2][4096];
  __shared__ float c2s[NC];
  __shared__ float rinv_sh[64];
  __shared__ float cnt_lds[NC];

  const int t    = threadIdx.x;
  const int wave = t >> 6;
  const int lane = t & 63;
  const int lx   = lane & 15;   // cluster-in-tile / D col
  const int gy   = lane >> 4;   // k-group / D row-group
  const int rowW = blockIdx.x * 64 + wave * 16;

  cnt_lds[t] = 0.f; cnt_lds[t + 256] = 0.f;
  c2s[t] = c2[t];   c2s[t + 256] = c2[t + 256];

  // ---- A fragments: this wave's 16 W rows, bf16 hi/lo (64 VGPR) ----
  bf16x8 ah[8], al[8];
  {
    const float* wrow = W + (size_t)(rowW + lx) * DIM;
    #pragma unroll
    for (int kc = 0; kc < 8; ++kc) {
      const float* p = wrow + kc * 32 + gy * 8;
      float4 v0 = *(const float4*)p;
      float4 v1 = *(const float4*)(p + 4);
      float xs[8] = {v0.x, v0.y, v0.z, v0.w, v1.x, v1.y, v1.z, v1.w};
      #pragma unroll
      for (int j = 0; j < 8; ++j) {
        unsigned short h = f2bf(xs[j]);
        ah[kc][j] = (short)h;
        al[kc][j] = (short)f2bf(xs[j] - bf2f(h));
      }
    }
  }
  float w2r[4];
  #pragma unroll
  for (int r = 0; r < 4; ++r) w2r[r] = w2[rowW + gy * 4 + r];

  float rowP[4] = {0.f, 0.f, 0.f, 0.f};
  float4 sh[2], sl[2];   // staging registers

  // stage_load: fetch tile ct's chunk for this thread (global -> regs).
  // chunk L = p*256+t maps to LDS 16B slot L (k-major), global (r,kc,g).
  #define STAGE_LOAD(ct_)                                              \
    { _Pragma("unroll")                                                \
      for (int p = 0; p < 2; ++p) {                                    \
        int L = p * 256 + t;                                           \
        int kc = L >> 6, r = (L >> 2) & 15, g = L & 3;                 \
        int off = ((ct_) * 16 + r) * 256 + kc * 32 + g * 8;            \
        sh[p] = *(const float4*)(Chi + off);                           \
        sl[p] = *(const float4*)(Clo + off);                           \
      } }
  #define STAGE_WRITE(b_)                                              \
    { _Pragma("unroll")                                                \
      for (int p = 0; p < 2; ++p) {                                    \
        int L = p * 256 + t;                                           \
        *(float4*)&Bh[b_][L * 8] = sh[p];                              \
        *(float4*)&Bl[b_][L * 8] = sl[p];                              \
      } }

  STAGE_LOAD(0)
  STAGE_WRITE(0)
  __syncthreads();

  for (int ct = 0; ct < 32; ++ct) {
    const int cur = ct & 1;
    if (ct < 31) STAGE_LOAD(ct + 1)          // overlap HBM/L2 latency with MFMA

    f32x4 aHH = {0.f,0.f,0.f,0.f}, aLH = {0.f,0.f,0.f,0.f}, aHL = {0.f,0.f,0.f,0.f};
    #pragma unroll
    for (int kc = 0; kc < 8; ++kc) {
      bf16x8 bh = *(const bf16x8*)&Bh[cur][kc * 512 + lx * 32 + gy * 8];
      bf16x8 bl = *(const bf16x8*)&Bl[cur][kc * 512 + lx * 32 + gy * 8];
      aHH = __builtin_amdgcn_mfma_f32_16x16x32_bf16(ah[kc], bh, aHH, 0, 0, 0);
      aLH = __builtin_amdgcn_mfma_f32_16x16x32_bf16(al[kc], bh, aLH, 0, 0, 0);
      aHL = __builtin_amdgcn_mfma_f32_16x16x32_bf16(ah[kc], bl, aHL, 0, 0, 0);
    }
    float c2v = c2s[ct * 16 + lx];
    #pragma unroll
    for (int r = 0; r < 4; ++r) {
      float dot = aHH[r] + aLH[r] + aHL[r];
      float d2  = w2r[r] + c2v - 2.f * dot;
      float e   = __expf(-sqrtf(fmaxf(d2, 1e-12f)));
      rowP[r] += e;
      attn[(size_t)(rowW + gy * 4 + r) * NC + ct * 16 + lx] = e;   // unnormalized
    }
    __syncthreads();
    if (ct < 31) { STAGE_WRITE(cur ^ 1) __syncthreads(); }
  }

  // ---- row sums -> rinv (reduce over the 16 lanes sharing each row set) ----
  #pragma unroll
  for (int m = 1; m < 16; m <<= 1) {
    #pragma unroll
    for (int r = 0; r < 4; ++r) rowP[r] += __shfl_xor(rowP[r], m);
  }
  if (lx == 0) {
    #pragma unroll
    for (int r = 0; r < 4; ++r) rinv_sh[wave * 16 + gy * 4 + r] = 1.f / rowP[r];
  }
  __syncthreads();   // publishes rinv_sh; drains e-stores (vmcnt) for phase 2

  // ---- phase 2: normalize own 64x512 block, coalesced; accumulate counts ----
  {
    float cs0 = 0.f, cs1 = 0.f, cs2 = 0.f, cs3 = 0.f;
    const int c0 = (t * 4) & 511;
    const size_t base = (size_t)blockIdx.x * 64 * NC;
    #pragma unroll 4
    for (int p = 0; p < 32; ++p) {
      int idx = p * 1024 + t * 4;
      int row = idx >> 9;
      float rv = rinv_sh[row];
      float* g = attn + base + (size_t)row * NC + c0;
      float4 v = *(float4*)g;
      v.x *= rv; v.y *= rv; v.z *= rv; v.w *= rv;
      *(float4*)g = v;
      cs0 += v.x; cs1 += v.y; cs2 += v.z; cs3 += v.w;
    }
    atomicAdd(&cnt_lds[c0 + 0], cs0);
    atomicAdd(&cnt_lds[c0 + 1], cs1);
    atomicAdd(&cnt_lds[c0 + 2], cs2);
    atomicAdd(&cnt_lds[c0 + 3], cs3);
  }
  __syncthreads();
  atomicAdd(&counts[t],       cnt_lds[t]);
  atomicAdd(&counts[t + 256], cnt_lds[t + 256]);
}

// ---------------- wsum = attn^T @ W (K-split, atomic epilogue) ----------------
__launch_bounds__(256, 2)
__global__ void k_wsum(const float* __restrict__ attn, const float* __restrict__ W,
                       float* __restrict__ wsum, const int* __restrict__ done)
{
  if (*done) return;
  __shared__ float At[64*64];
  __shared__ float Bt[64*64];
  const int t = threadIdx.x, tx = t & 15, ty = t >> 4;
  const int ctile = blockIdx.x & 7;
  const int dtile = (blockIdx.x >> 3) & 3;
  const int kch   = blockIdx.x >> 5;
  const int c0 = ctile*64, d0 = dtile*64;
  const size_t rbase = (size_t)kch * 2048;
  float acc[4][4] = {{0}};
  for (int kk = 0; kk < 2048; kk += 64) {
    __syncthreads();
    #pragma unroll
    for (int p = 0; p < 4; ++p) {
      int q = p*256 + t;
      int kr = q >> 4, c4 = q & 15;
      size_t row = rbase + kk + kr;
      *(float4*)&At[kr*64 + 4*c4] = *(const float4*)(attn + row*NC  + c0 + 4*c4);
      *(float4*)&Bt[kr*64 + 4*c4] = *(const float4*)(W    + row*DIM + d0 + 4*c4);
    }
    __syncthreads();
    #pragma unroll 8
    for (int k = 0; k < 64; ++k) {
      float4 av = *(const float4*)&At[k*64 + 4*ty];
      float4 bv = *(const float4*)&Bt[k*64 + 4*tx];
      acc[0][0]+=av.x*bv.x; acc[0][1]+=av.x*bv.y; acc[0][2]+=av.x*bv.z; acc[0][3]+=av.x*bv.w;
      acc[1][0]+=av.y*bv.x; acc[1][1]+=av.y*bv.y; acc[1][2]+=av.y*bv.z; acc[1][3]+=av.y*bv.w;
      acc[2][0]+=av.z*bv.x; acc[2][1]+=av.z*bv.y; acc[2][2]+=av.z*bv.z; acc[2][3]+=av.z*bv.w;
      acc[3][0]+=av.w*bv.x; acc[3][1]+=av.w*bv.y; acc[3][2]+=av.w*bv.z; acc[3][3]+=av.w*bv.w;
    }
  }
  #pragma unroll
  for (int i = 0; i < 4; ++i)
    #pragma unroll
    for (int j = 0; j < 4; ++j)
      atomicAdd(&wsum[(size_t)(c0 + 4*ty + i)*DIM + d0 + 4*tx + j], acc[i][j]);
}

// ---------------- cluster update + convergence ----------------
__global__ void k_update(float* __restrict__ C, const float* __restrict__ wsum,
                         const float* __restrict__ counts, int* __restrict__ done)
{
  if (*done) return;
  __shared__ float wsh[16];
  __shared__ float nrm2;
  int t = threadIdx.x;  // 1024
  float local = 0.f;
  for (int p = 0; p < 128; ++p) {
    int i = p*1024 + t;
    float cn = wsum[i] / counts[i >> 8];
    float d  = C[i] - cn;
    local += d * d;
  }
  #pragma unroll
  for (int o = 32; o; o >>= 1) local += __shfl_down(local, o);
  if ((t & 63) == 0) wsh[t >> 6] = local;
  __syncthreads();
  if (t == 0) {
    float s = 0.f;
    #pragma unroll
    for (int x = 0; x < 16; ++x) s += wsh[x];
    nrm2 = s;
  }
  __syncthreads();
  if (nrm2 <= 1e-8f) {
    if (t == 0) *done = 1;
  } else {
    for (int p = 0; p < 128; ++p) {
      int i = p*1024 + t;
      C[i] = wsum[i] / counts[i >> 8];
    }
  }
}

// ---------------- compressed = attn @ C ----------------
__device__ __forceinline__ int swz64(int k, int c) {
  return (k << 6) + (c ^ (((k >> 2) & 15) << 2));
}
__launch_bounds__(256, 2)
__global__ void k_compress(const float* __restrict__ attn, const float* __restrict__ C,
                           float* __restrict__ out)
{
  __shared__ float At[64*64];
  __shared__ float Bt[64*64];
  const int t = threadIdx.x, tx = t & 15, ty = t >> 4;
  const int rt = blockIdx.x >> 2;
  const int dt = blockIdx.x & 3;
  const int r0 = rt*64, d0 = dt*64;
  float acc[4][4] = {{0}};
  for (int kc = 0; kc < 8; ++kc) {
    __syncthreads();
    #pragma unroll
    for (int p = 0; p < 4; ++p) {
      int q = p*256 + t;
      int r = q >> 4, x4 = q & 15;
      float4 v = *(const float4*)(attn + (size_t)(r0 + r)*NC + kc*64 + 4*x4);
      At[swz64(4*x4+0, r)] = v.x;
      At[swz64(4*x4+1, r)] = v.y;
      At[swz64(4*x4+2, r)] = v.z;
      At[swz64(4*x4+3, r)] = v.w;
      *(float4*)&Bt[r*64 + 4*x4] = *(const float4*)(C + (size_t)(kc*64 + r)*DIM + d0 + 4*x4);
    }
    __syncthreads();
    #pragma unroll 8
    for (int k = 0; k < 64; ++k) {
      float4 av = *(const float4*)&At[swz64(k, 4*ty)];
      float4 bv = *(const float4*)&Bt[k*64 + 4*tx];
      acc[0][0]+=av.x*bv.x; acc[0][1]+=av.x*bv.y; acc[0][2]+=av.x*bv.z; acc[0][3]+=av.x*bv.w;
      acc[1][0]+=av.y*bv.x; acc[1][1]+=av.y*bv.y; acc[1][2]+=av.y*bv.z; acc[1][3]+=av.y*bv.w;
      acc[2][0]+=av.z*bv.x; acc[2][1]+=av.z*bv.y; acc[2][2]+=av.z*bv.z; acc[2][3]+=av.z*bv.w;
      acc[3][0]+=av.w*bv.x; acc[3][1]+=av.w*bv.y; acc[3][2]+=av.w*bv.z; acc[3][3]+=av.w*bv.w;
    }
  }
  #pragma unroll
  for (int i = 0; i < 4; ++i) {
    float4 o = {acc[i][0], acc[i][1], acc[i][2], acc[i][3]};
    *(float4*)(out + (size_t)(r0 + 4*ty + i)*DIM + d0 + 4*tx) = o;
  }
}

__global__ void k_copy(const float* __restrict__ C, float* __restrict__ out) {
  int i = blockIdx.x * 256 + threadIdx.x;
  out[i] = C[i];
}

extern "C" void kernel_launch(void* const* d_in, const int* in_sizes, int n_in,
                              void* d_out, int out_size, void* d_ws, size_t ws_size,
                              hipStream_t stream)
{
  const float* W = (const float*)d_in[0];
  float* out = (float*)d_out;
  float* compressed   = out;
  float* out_clusters = out + (size_t)NPTS * DIM;
  float* attn         = out_clusters + NC * DIM;

  float* ws     = (float*)d_ws;
  float* C      = ws + WS_C;
  float* wsum   = ws + WS_WSUM;
  float* counts = ws + WS_COUNTS;
  float* w2     = ws + WS_W2;
  float* c2     = ws + WS_C2;
  int*   done   = (int*)(ws + WS_DONE);
  unsigned short* Chi = (unsigned short*)(ws + WS_CHI);
  unsigned short* Clo = (unsigned short*)(ws + WS_CLO);

  k_init<<<NC*DIM/256, 256, 0, stream>>>(W, C, done);
  k_w2<<<NPTS/4, 256, 0, stream>>>(W, w2);
  for (int it = 0; it < NITER; ++it) {
    k_prep<<<NC, 256, 0, stream>>>(C, c2, wsum, counts, Chi, Clo);
    k_attn<<<NPTS/64, 256, 0, stream>>>(W, Chi, Clo, w2, c2, attn, counts, done);
    k_wsum<<<1024, 256, 0, stream>>>(attn, W, wsum, done);
    k_update<<<1, 1024, 0, stream>>>(C, wsum, counts, done);
  }
  k_compress<<<(NPTS/64)*(DIM/64), 256, 0, stream>>>(attn, C, compressed);
  k_copy<<<NC*DIM/256, 256, 0, stream>>>(C, out_clusters);
}

// Round 7
// 3730.658 us; speedup vs baseline: 1.6148x; 1.1686x over previous
//
#include <hip/hip_runtime.h>
#include <math.h>

#define NPTS  65536
#define DIM   256
#define NC    512
#define NITER 10

// ---------------- workspace layout (float offsets) ----------------
#define WS_C      0                        // clusters      512*256
#define WS_WSUM   (WS_C + NC*DIM)          // weighted sums 512*256
#define WS_CNEW   (WS_WSUM + NC*DIM)       // new clusters  512*256
#define WS_COUNTS (WS_CNEW + NC*DIM)       // counts        512
#define WS_W2     (WS_COUNTS + NC)         // ||w||^2       65536
#define WS_C2     (WS_W2 + NPTS)           // ||c||^2       512
#define WS_RINV   (WS_C2 + NC)             // 1/rowsum      65536
#define WS_DONE   (WS_RINV + NPTS)         // done flag (int)
#define WS_NRM    (WS_DONE + 1)            // ||dC||^2
#define WS_CHI    (WS_DONE + 7)            // C hi bf16 (16B-aligned)
#define WS_CLO    (WS_CHI + NC*DIM/2)      // C lo bf16

typedef __attribute__((ext_vector_type(8))) short bf16x8;
typedef __attribute__((ext_vector_type(4))) float f32x4;

__device__ __forceinline__ unsigned short f2bf(float x) {
  unsigned u = __float_as_uint(x);
  u += 0x7fffu + ((u >> 16) & 1u);
  return (unsigned short)(u >> 16);
}
__device__ __forceinline__ float bf2f(unsigned short h) {
  return __uint_as_float(((unsigned)h) << 16);
}

// ---------------- init ----------------
__global__ void k_init(const float* __restrict__ W, float* __restrict__ C, int* __restrict__ done) {
  int i = blockIdx.x * 256 + threadIdx.x;
  C[i] = W[i];
  if (i == 0) *done = 0;
}

__global__ void k_w2(const float* __restrict__ W, float* __restrict__ w2) {
  int row  = blockIdx.x * 4 + (threadIdx.x >> 6);
  int lane = threadIdx.x & 63;
  float4 v = *(const float4*)(W + (size_t)row * DIM + 4 * lane);
  float s = v.x*v.x + v.y*v.y + v.z*v.z + v.w*v.w;
  #pragma unroll
  for (int o = 32; o; o >>= 1) s += __shfl_down(s, o);
  if (lane == 0) w2[row] = s;
}

// ---------------- per-iter prep ----------------
__global__ void k_prep(const float* __restrict__ C, float* __restrict__ c2,
                       float* __restrict__ wsum, float* __restrict__ counts,
                       unsigned short* __restrict__ Chi, unsigned short* __restrict__ Clo,
                       float* __restrict__ nrm2) {
  __shared__ float wsh[4];
  int b = blockIdx.x, t = threadIdx.x;
  float v = C[b * DIM + t];
  unsigned short h = f2bf(v);
  Chi[b * DIM + t] = h;
  Clo[b * DIM + t] = f2bf(v - bf2f(h));
  float s = v * v;
  #pragma unroll
  for (int o = 32; o; o >>= 1) s += __shfl_down(s, o);
  if ((t & 63) == 0) wsh[t >> 6] = s;
  __syncthreads();
  if (t == 0) c2[b] = wsh[0] + wsh[1] + wsh[2] + wsh[3];
  wsum[b * DIM + t] = 0.f;
  if (t == 0) counts[b] = 0.f;
  if (b == 0 && t == 0) *nrm2 = 0.f;
}

// ---------------- distances + exp (split-bf16 MFMA); writes e + rinv ----------
// 1024 blocks x 4 waves; wave = 16 rows x 512 clusters.
// e stores go through a wave-private LDS buffer so each global store writes
// one FULL 128B line per row (kills the partial-line write amplification).
__launch_bounds__(256, 4)
__global__ void k_attn(const float* __restrict__ W,
                       const unsigned short* __restrict__ Chi,
                       const unsigned short* __restrict__ Clo,
                       const float* __restrict__ w2, const float* __restrict__ c2,
                       float* __restrict__ attn, float* __restrict__ rinv,
                       const int* __restrict__ done)
{
  if (*done) return;
  __shared__ unsigned short Bh[4096];      // [kc:8][r:16][gy:4][8] bf16, 8 KB
  __shared__ unsigned short Bl[4096];
  __shared__ float c2s[NC];
  __shared__ float ebuf[4][16][36];        // per-wave e staging (2 ct tiles)

  const int t    = threadIdx.x;
  const int wave = t >> 6;
  const int lane = t & 63;
  const int lx   = lane & 15;
  const int gy   = lane >> 4;
  const int rowW = blockIdx.x * 64 + wave * 16;

  c2s[t] = c2[t];  c2s[t + 256] = c2[t + 256];

  // ---- A fragments: wave's 16 W rows, bf16 hi/lo ----
  bf16x8 ah[8], al[8];
  {
    const float* wrow = W + (size_t)(rowW + lx) * DIM;
    #pragma unroll
    for (int kc = 0; kc < 8; ++kc) {
      const float* p = wrow + kc * 32 + gy * 8;
      float4 v0 = *(const float4*)p;
      float4 v1 = *(const float4*)(p + 4);
      float xs[8] = {v0.x, v0.y, v0.z, v0.w, v1.x, v1.y, v1.z, v1.w};
      #pragma unroll
      for (int j = 0; j < 8; ++j) {
        unsigned short h = f2bf(xs[j]);
        ah[kc][j] = (short)h;
        al[kc][j] = (short)f2bf(xs[j] - bf2f(h));
      }
    }
  }
  float w2r[4];
  #pragma unroll
  for (int r = 0; r < 4; ++r) w2r[r] = w2[rowW + gy * 4 + r];

  float rowP[4] = {0.f, 0.f, 0.f, 0.f};
  float4 sh[2], sl[2];

  // prologue: stage tile 0 (global -> regs -> LDS)
  #pragma unroll
  for (int p = 0; p < 2; ++p) {
    int L = p * 256 + t;
    int kc = L >> 6, r = (L >> 2) & 15, g = L & 3;
    int off = r * 256 + kc * 32 + g * 8;
    sh[p] = *(const float4*)(Chi + off);
    sl[p] = *(const float4*)(Clo + off);
  }
  #pragma unroll
  for (int p = 0; p < 2; ++p) {
    int L = p * 256 + t;
    *(float4*)&Bh[L * 8] = sh[p];
    *(float4*)&Bl[L * 8] = sl[p];
  }
  __syncthreads();

  for (int ct = 0; ct < 32; ++ct) {
    if (ct < 31) {                          // prefetch next tile into regs
      #pragma unroll
      for (int p = 0; p < 2; ++p) {
        int L = p * 256 + t;
        int kc = L >> 6, r = (L >> 2) & 15, g = L & 3;
        int off = ((ct + 1) * 16 + r) * 256 + kc * 32 + g * 8;
        sh[p] = *(const float4*)(Chi + off);
        sl[p] = *(const float4*)(Clo + off);
      }
    }
    f32x4 aHH = {0.f,0.f,0.f,0.f}, aLH = {0.f,0.f,0.f,0.f}, aHL = {0.f,0.f,0.f,0.f};
    #pragma unroll
    for (int kc = 0; kc < 8; ++kc) {
      bf16x8 bh = *(const bf16x8*)&Bh[kc * 512 + lx * 32 + gy * 8];
      bf16x8 bl = *(const bf16x8*)&Bl[kc * 512 + lx * 32 + gy * 8];
      aHH = __builtin_amdgcn_mfma_f32_16x16x32_bf16(ah[kc], bh, aHH, 0, 0, 0);
      aLH = __builtin_amdgcn_mfma_f32_16x16x32_bf16(al[kc], bh, aLH, 0, 0, 0);
      aHL = __builtin_amdgcn_mfma_f32_16x16x32_bf16(ah[kc], bl, aHL, 0, 0, 0);
    }
    float c2v = c2s[ct * 16 + lx];
    #pragma unroll
    for (int r = 0; r < 4; ++r) {
      float dot = aHH[r] + aLH[r] + aHL[r];
      float d2  = w2r[r] + c2v - 2.f * dot;
      float e   = __expf(-sqrtf(fmaxf(d2, 1e-12f)));
      rowP[r] += e;
      ebuf[wave][gy * 4 + r][(ct & 1) * 16 + lx] = e;
    }
    if (ct & 1) {                           // flush 16 rows x 32 cols: full lines
      #pragma unroll
      for (int q = 0; q < 2; ++q) {
        int r = q * 8 + (lane >> 3);
        int c = (lane & 7) * 4;
        float4 v = *(const float4*)&ebuf[wave][r][c];
        *(float4*)(attn + (size_t)(rowW + r) * NC + (ct & ~1) * 16 + c) = v;
      }
    }
    __syncthreads();                        // all waves done reading Bh/Bl
    if (ct < 31) {
      #pragma unroll
      for (int p = 0; p < 2; ++p) {
        int L = p * 256 + t;
        *(float4*)&Bh[L * 8] = sh[p];
        *(float4*)&Bl[L * 8] = sl[p];
      }
      __syncthreads();                      // LDS ready for next ct
    }
  }

  #pragma unroll
  for (int m = 1; m < 16; m <<= 1) {
    #pragma unroll
    for (int r = 0; r < 4; ++r) rowP[r] += __shfl_xor(rowP[r], m);
  }
  if (lx == 0) {
    #pragma unroll
    for (int r = 0; r < 4; ++r) rinv[rowW + gy * 4 + r] = 1.f / rowP[r];
  }
}

// ---------------- wsum = (e*rinv)^T @ W ; counts folded in ----------------
__launch_bounds__(256, 2)
__global__ void k_wsum(const float* __restrict__ attn, const float* __restrict__ W,
                       const float* __restrict__ rinv,
                       float* __restrict__ wsum, float* __restrict__ counts,
                       const int* __restrict__ done)
{
  if (*done) return;
  __shared__ float At[64*64];
  __shared__ float Bt[64*64];
  __shared__ float cnt_sh[64];
  const int t = threadIdx.x, tx = t & 15, ty = t >> 4;
  const int ctile = blockIdx.x & 7;
  const int dtile = (blockIdx.x >> 3) & 3;
  const int kch   = blockIdx.x >> 5;
  const int c0 = ctile*64, d0 = dtile*64;
  const size_t rbase = (size_t)kch * 2048;
  const bool do_cnt = (dtile == 0);
  if (t < 64) cnt_sh[t] = 0.f;
  float cs0 = 0.f, cs1 = 0.f, cs2 = 0.f, cs3 = 0.f;
  float acc[4][4] = {{0}};
  for (int kk = 0; kk < 2048; kk += 64) {
    __syncthreads();
    #pragma unroll
    for (int p = 0; p < 4; ++p) {
      int q = p*256 + t;
      int kr = q >> 4, c4 = q & 15;
      size_t row = rbase + kk + kr;
      float4 a = *(const float4*)(attn + row*NC + c0 + 4*c4);
      float rv = rinv[row];
      a.x *= rv; a.y *= rv; a.z *= rv; a.w *= rv;
      if (do_cnt) { cs0 += a.x; cs1 += a.y; cs2 += a.z; cs3 += a.w; }
      *(float4*)&At[kr*64 + 4*c4] = a;
      *(float4*)&Bt[kr*64 + 4*c4] = *(const float4*)(W + row*DIM + d0 + 4*c4);
    }
    __syncthreads();
    #pragma unroll 8
    for (int k = 0; k < 64; ++k) {
      float4 av = *(const float4*)&At[k*64 + 4*ty];
      float4 bv = *(const float4*)&Bt[k*64 + 4*tx];
      acc[0][0]+=av.x*bv.x; acc[0][1]+=av.x*bv.y; acc[0][2]+=av.x*bv.z; acc[0][3]+=av.x*bv.w;
      acc[1][0]+=av.y*bv.x; acc[1][1]+=av.y*bv.y; acc[1][2]+=av.y*bv.z; acc[1][3]+=av.y*bv.w;
      acc[2][0]+=av.z*bv.x; acc[2][1]+=av.z*bv.y; acc[2][2]+=av.z*bv.z; acc[2][3]+=av.z*bv.w;
      acc[3][0]+=av.w*bv.x; acc[3][1]+=av.w*bv.y; acc[3][2]+=av.w*bv.z; acc[3][3]+=av.w*bv.w;
    }
  }
  #pragma unroll
  for (int i = 0; i < 4; ++i)
    #pragma unroll
    for (int j = 0; j < 4; ++j)
      atomicAdd(&wsum[(size_t)(c0 + 4*ty + i)*DIM + d0 + 4*tx + j], acc[i][j]);
  if (do_cnt) {
    atomicAdd(&cnt_sh[4*tx + 0], cs0);
    atomicAdd(&cnt_sh[4*tx + 1], cs1);
    atomicAdd(&cnt_sh[4*tx + 2], cs2);
    atomicAdd(&cnt_sh[4*tx + 3], cs3);
    __syncthreads();
    if (t < 64) atomicAdd(&counts[c0 + t], cnt_sh[t]);
  }
}

// ---------------- cluster update (2-stage, parallel) ----------------
__global__ void k_updA(const float* __restrict__ C, const float* __restrict__ wsum,
                       const float* __restrict__ counts, float* __restrict__ Cnew,
                       float* __restrict__ nrm2, const int* __restrict__ done)
{
  if (*done) return;
  __shared__ float sh[4];
  int i = blockIdx.x * 256 + threadIdx.x;
  float cn = wsum[i] / counts[i >> 8];
  Cnew[i] = cn;
  float d = C[i] - cn;
  float s = d * d;
  #pragma unroll
  for (int o = 32; o; o >>= 1) s += __shfl_down(s, o);
  if ((threadIdx.x & 63) == 0) sh[threadIdx.x >> 6] = s;
  __syncthreads();
  if (threadIdx.x == 0) atomicAdd(nrm2, sh[0] + sh[1] + sh[2] + sh[3]);
}
__global__ void k_updB(float* __restrict__ C, const float* __restrict__ Cnew,
                       const float* __restrict__ nrm2, int* __restrict__ done)
{
  if (*done) return;
  if (*nrm2 <= 1e-8f) {                 // ||dC|| <= 1e-4 -> freeze
    if (blockIdx.x == 0 && threadIdx.x == 0) *done = 1;
  } else {
    int i = blockIdx.x * 256 + threadIdx.x;
    C[i] = Cnew[i];
  }
}

// ---------------- final normalize: attn = e * rinv[row], in place ----------
__global__ void k_norm(float* __restrict__ attn, const float* __restrict__ rinv) {
  size_t i = ((size_t)blockIdx.x * 256 + threadIdx.x) * 4;
  float rv = rinv[i >> 9];
  float4 v = *(float4*)(attn + i);
  v.x *= rv; v.y *= rv; v.z *= rv; v.w *= rv;
  *(float4*)(attn + i) = v;
}

// ---------------- compressed = attn @ C ----------------
__device__ __forceinline__ int swz64(int k, int c) {
  return (k << 6) + (c ^ (((k >> 2) & 15) << 2));
}
__launch_bounds__(256, 2)
__global__ void k_compress(const float* __restrict__ attn, const float* __restrict__ C,
                           float* __restrict__ out)
{
  __shared__ float At[64*64];
  __shared__ float Bt[64*64];
  const int t = threadIdx.x, tx = t & 15, ty = t >> 4;
  const int rt = blockIdx.x >> 2;
  const int dt = blockIdx.x & 3;
  const int r0 = rt*64, d0 = dt*64;
  float acc[4][4] = {{0}};
  for (int kc = 0; kc < 8; ++kc) {
    __syncthreads();
    #pragma unroll
    for (int p = 0; p < 4; ++p) {
      int q = p*256 + t;
      int r = q >> 4, x4 = q & 15;
      float4 v = *(const float4*)(attn + (size_t)(r0 + r)*NC + kc*64 + 4*x4);
      At[swz64(4*x4+0, r)] = v.x;
      At[swz64(4*x4+1, r)] = v.y;
      At[swz64(4*x4+2, r)] = v.z;
      At[swz64(4*x4+3, r)] = v.w;
      *(float4*)&Bt[r*64 + 4*x4] = *(const float4*)(C + (size_t)(kc*64 + r)*DIM + d0 + 4*x4);
    }
    __syncthreads();
    #pragma unroll 8
    for (int k = 0; k < 64; ++k) {
      float4 av = *(const float4*)&At[swz64(k, 4*ty)];
      float4 bv = *(const float4*)&Bt[k*64 + 4*tx];
      acc[0][0]+=av.x*bv.x; acc[0][1]+=av.x*bv.y; acc[0][2]+=av.x*bv.z; acc[0][3]+=av.x*bv.w;
      acc[1][0]+=av.y*bv.x; acc[1][1]+=av.y*bv.y; acc[1][2]+=av.y*bv.z; acc[1][3]+=av.y*bv.w;
      acc[2][0]+=av.z*bv.x; acc[2][1]+=av.z*bv.y; acc[2][2]+=av.z*bv.z; acc[2][3]+=av.z*bv.w;
      acc[3][0]+=av.w*bv.x; acc[3][1]+=av.w*bv.y; acc[3][2]+=av.w*bv.z; acc[3][3]+=av.w*bv.w;
    }
  }
  #pragma unroll
  for (int i = 0; i < 4; ++i) {
    float4 o = {acc[i][0], acc[i][1], acc[i][2], acc[i][3]};
    *(float4*)(out + (size_t)(r0 + 4*ty + i)*DIM + d0 + 4*tx) = o;
  }
}

__global__ void k_copy(const float* __restrict__ C, float* __restrict__ out) {
  int i = blockIdx.x * 256 + threadIdx.x;
  out[i] = C[i];
}

extern "C" void kernel_launch(void* const* d_in, const int* in_sizes, int n_in,
                              void* d_out, int out_size, void* d_ws, size_t ws_size,
                              hipStream_t stream)
{
  const float* W = (const float*)d_in[0];
  float* out = (float*)d_out;
  float* compressed   = out;
  float* out_clusters = out + (size_t)NPTS * DIM;
  float* attn         = out_clusters + NC * DIM;

  float* ws     = (float*)d_ws;
  float* C      = ws + WS_C;
  float* wsum   = ws + WS_WSUM;
  float* Cnew   = ws + WS_CNEW;
  float* counts = ws + WS_COUNTS;
  float* w2     = ws + WS_W2;
  float* c2     = ws + WS_C2;
  float* rinv   = ws + WS_RINV;
  int*   done   = (int*)(ws + WS_DONE);
  float* nrm2   = ws + WS_NRM;
  unsigned short* Chi = (unsigned short*)(ws + WS_CHI);
  unsigned short* Clo = (unsigned short*)(ws + WS_CLO);

  k_init<<<NC*DIM/256, 256, 0, stream>>>(W, C, done);
  k_w2<<<NPTS/4, 256, 0, stream>>>(W, w2);
  for (int it = 0; it < NITER; ++it) {
    k_prep<<<NC, 256, 0, stream>>>(C, c2, wsum, counts, Chi, Clo, nrm2);
    k_attn<<<NPTS/64, 256, 0, stream>>>(W, Chi, Clo, w2, c2, attn, rinv, done);
    k_wsum<<<1024, 256, 0, stream>>>(attn, W, rinv, wsum, counts, done);
    k_updA<<<NC*DIM/256, 256, 0, stream>>>(C, wsum, counts, Cnew, nrm2, done);
    k_updB<<<NC*DIM/256, 256, 0, stream>>>(C, Cnew, nrm2, done);
  }
  k_norm<<<NPTS*NC/1024, 256, 0, stream>>>(attn, rinv);
  k_compress<<<(NPTS/64)*(DIM/64), 256, 0, stream>>>(attn, C, compressed);
  k_copy<<<NC*DIM/256, 256, 0, stream>>>(C, out_clusters);
}